// Round 6
// baseline (2730.988 us; speedup 1.0000x reference)
//
#include <hip/hip_runtime.h>
#include <hip/hip_bf16.h>

#define BB 256
#define TT 128
#define NN 1024
#define HH 1024
#define G4 4096

typedef __attribute__((ext_vector_type(4))) float f32x4;
typedef __attribute__((ext_vector_type(8))) short bf16x8;

__device__ __forceinline__ unsigned short f2bf(float f) {
    unsigned int u = __builtin_bit_cast(unsigned int, f);
    u += 0x7FFFu + ((u >> 16) & 1u);
    return (unsigned short)(u >> 16);
}
__device__ __forceinline__ float bf2f(unsigned short s) {
    unsigned int u = ((unsigned int)s) << 16;
    return __builtin_bit_cast(float, u);
}

// ---------------------------------------------------------------------------
// K1: attention weights (time-invariant) + input_weighted (f32) + w_in bf16
// ---------------------------------------------------------------------------
__global__ __launch_bounds__(512) void k_attn(
    const float* __restrict__ x, const float* __restrict__ attn_w,
    const float* __restrict__ attn_b, float* __restrict__ out0,
    unsigned short* __restrict__ win_bf)
{
    const int b = blockIdx.x;
    const int tid = threadIdx.x;
    const float* xb = x + (size_t)b * (TT * NN);
    const float* wx = attn_w + 2 * HH;

    float s0 = 0.f, s1 = 0.f;
    for (int t = 0; t < TT; ++t) {
        float2 v = *(const float2*)(xb + (size_t)t * NN + tid * 2);
        float w = wx[t];
        s0 += v.x * w; s1 += v.y * w;
    }
    float ab = attn_b[0];
    s0 += ab; s1 += ab;

    __shared__ float red[8];
    const int wv = tid >> 6, ln = tid & 63;
    float m = fmaxf(s0, s1);
#pragma unroll
    for (int off = 32; off > 0; off >>= 1) m = fmaxf(m, __shfl_xor(m, off));
    if (ln == 0) red[wv] = m;
    __syncthreads();
    m = red[0];
#pragma unroll
    for (int i = 1; i < 8; ++i) m = fmaxf(m, red[i]);

    float e0 = expf(s0 - m), e1 = expf(s1 - m);
    float sum = e0 + e1;
#pragma unroll
    for (int off = 32; off > 0; off >>= 1) sum += __shfl_xor(sum, off);
    __syncthreads();
    if (ln == 0) red[wv] = sum;
    __syncthreads();
    sum = 0.f;
#pragma unroll
    for (int i = 0; i < 8; ++i) sum += red[i];
    const float inv = 1.0f / sum;
    const float a0 = e0 * inv, a1 = e1 * inv;

    float* o = out0 + (size_t)b * (TT * NN);
    unsigned short* wb = win_bf + (size_t)b * (TT * NN);
    for (int t = 0; t < TT; ++t) {
        float2 v = *(const float2*)(xb + (size_t)t * NN + tid * 2);
        float2 w; w.x = a0 * v.x; w.y = a1 * v.y;
        *(float2*)(o + (size_t)t * NN + tid * 2) = w;
        unsigned int pk = (unsigned int)f2bf(w.x) | ((unsigned int)f2bf(w.y) << 16);
        *(unsigned int*)(wb + (size_t)t * NN + tid * 2) = pk;
    }
}

// ---------------------------------------------------------------------------
// K2: convert W_ih / W_hh to bf16 with gate-interleaved row perm p=j*4+g
// ---------------------------------------------------------------------------
__global__ __launch_bounds__(256) void k_prep_w(
    const float* __restrict__ Wih, const float* __restrict__ Whh,
    const float* __restrict__ bih, const float* __restrict__ bhh,
    unsigned short* __restrict__ WihP, unsigned short* __restrict__ WhhP,
    float* __restrict__ biasP)
{
    const int p = blockIdx.x;
    const int j = p >> 2, g = p & 3;
    const int r = g * HH + j;
    const int tid = threadIdx.x;
    {
        float4 v = *(const float4*)(Wih + (size_t)r * NN + tid * 4);
        ushort4 o;
        o.x = f2bf(v.x); o.y = f2bf(v.y); o.z = f2bf(v.z); o.w = f2bf(v.w);
        *(ushort4*)(WihP + (size_t)p * NN + tid * 4) = o;
    }
    {
        float4 v = *(const float4*)(Whh + (size_t)r * HH + tid * 4);
        ushort4 o;
        o.x = f2bf(v.x); o.y = f2bf(v.y); o.z = f2bf(v.z); o.w = f2bf(v.w);
        *(ushort4*)(WhhP + (size_t)p * HH + tid * 4) = o;
    }
    if (tid == 0) biasP[p] = bih[r] + bhh[r];
}

// ---------------------------------------------------------------------------
// K3: Xp = w_in_bf16 (32768,1024) @ WihP^T (4096,1024) -> bf16 (32768,4096)
// ---------------------------------------------------------------------------
__global__ __launch_bounds__(256) void k_gemm_xp(
    const unsigned short* __restrict__ A,
    const unsigned short* __restrict__ Bm,
    unsigned short* __restrict__ C)
{
    __shared__ unsigned short lA[128 * 32];
    __shared__ unsigned short lB[128 * 32];

    const int bid = blockIdx.x;
    const int cpx = gridDim.x >> 3;
    const int swz = (bid & 7) * cpx + (bid >> 3);
    const int NTN = G4 / 128;
    const int tm = swz / NTN, tn = swz % NTN;

    const int tid = threadIdx.x;
    const int wv = tid >> 6, ln = tid & 63;
    const int wr = wv >> 1, wc = wv & 1;

    f32x4 acc[4][4] = {};

    const unsigned short* Ag = A + (size_t)tm * 128 * NN;
    const unsigned short* Bg = Bm + (size_t)tn * 128 * NN;
    const int srow = ln >> 2;
    const int sseg = ln & 3;

    for (int k0 = 0; k0 < NN; k0 += 32) {
        __syncthreads();
#pragma unroll
        for (int q = 0; q < 2; ++q) {
            const int row = wv * 32 + q * 16 + srow;
            __builtin_amdgcn_global_load_lds(
                (const __attribute__((address_space(1))) void*)(Ag + (size_t)row * NN + k0 + sseg * 8),
                (__attribute__((address_space(3))) void*)(&lA[(wv * 32 + q * 16) * 32]),
                16, 0, 0);
            __builtin_amdgcn_global_load_lds(
                (const __attribute__((address_space(1))) void*)(Bg + (size_t)row * NN + k0 + sseg * 8),
                (__attribute__((address_space(3))) void*)(&lB[(wv * 32 + q * 16) * 32]),
                16, 0, 0);
        }
        __syncthreads();

        const int rlo = ln & 15, khi = ln >> 4;
        bf16x8 af[4], bfr[4];
#pragma unroll
        for (int m = 0; m < 4; ++m)
            af[m] = *(const bf16x8*)&lA[(wr * 64 + m * 16 + rlo) * 32 + khi * 8];
#pragma unroll
        for (int n = 0; n < 4; ++n)
            bfr[n] = *(const bf16x8*)&lB[(wc * 64 + n * 16 + rlo) * 32 + khi * 8];
#pragma unroll
        for (int m = 0; m < 4; ++m)
#pragma unroll
            for (int n = 0; n < 4; ++n)
                acc[m][n] = __builtin_amdgcn_mfma_f32_16x16x32_bf16(af[m], bfr[n], acc[m][n], 0, 0, 0);
    }

    const int rlo = ln & 15, rhi = ln >> 4;
#pragma unroll
    for (int m = 0; m < 4; ++m)
#pragma unroll
        for (int n = 0; n < 4; ++n)
#pragma unroll
            for (int j = 0; j < 4; ++j) {
                const int row = tm * 128 + wr * 64 + m * 16 + rhi * 4 + j;
                const int col = tn * 128 + wc * 64 + n * 16 + rlo;
                C[(size_t)row * G4 + col] = f2bf(acc[m][n][j]);
            }
}

// ---------------------------------------------------------------------------
// K4-persistent v2: whole recurrence, hand-rolled SAME-TI producer barrier.
//   256 blocks x 512 threads (8 waves). Block (ti=bid>>6, tj=bid&63):
//   64 batches x 64 perm-cols. W_hh^perm slice LDS-resident (128 KiB,
//   XOR-swizzled). h: global bf16 dbuf; chunks streamed via 3x8 KiB LDS
//   rotation, ONE barrier/chunk, uniform vmcnt(1). c in registers. Xp
//   direct to registers. Sync: per-ti cumulative counter, RELEASE add /
//   relaxed poll + ACQUIRE (agent scope). NO grid.sync, no threadfence.
//   out1 via nontemporal stores so the release wbl2 has ~nothing to flush.
// ---------------------------------------------------------------------------
__global__ __launch_bounds__(512, 1) void k_recur2(
    const unsigned short* __restrict__ WhhP,
    const unsigned short* __restrict__ Xp,
    const float* __restrict__ biasP,
    unsigned short* __restrict__ h0,
    unsigned short* __restrict__ h1,
    unsigned int* __restrict__ ctr,
    float* __restrict__ out1)
{
    __shared__ unsigned short lB[64 * 1024];   // 128 KiB W slice
    __shared__ unsigned short lA[3][64 * 64];  //  24 KiB h chunk tri-buffer

    const int bid = blockIdx.x;
    const int ti = bid >> 6, tj = bid & 63;
    const int tid = threadIdx.x;
    const int wv = tid >> 6, ln = tid & 63;    // 8 waves
    const int wr = wv >> 1, wc = wv & 1;       // 16-row x 32-col wave tile
    const int rlo = ln & 15, khi = ln >> 4;

    // ---- W_hh slice -> LDS once (pre-swizzled src, linear dest) ----
    {
        const char* base = (const char*)WhhP + (size_t)(tj * 64) * 2048;
#pragma unroll
        for (int q = 0; q < 16; ++q) {
            const int i = wv * 16 + q;         // 0..127 -> 1 KiB each
            const int r = i >> 1, half = i & 1;
            const int lbo = (half * 1024 + ln * 16) ^ ((r & 7) << 4);
            __builtin_amdgcn_global_load_lds(
                (const __attribute__((address_space(1))) void*)(base + (size_t)r * 2048 + lbo),
                (__attribute__((address_space(3))) void*)((char*)lB + i * 1024),
                16, 0, 0);
        }
    }

    float4 bias4[2];
#pragma unroll
    for (int n = 0; n < 2; ++n)
        bias4[n] = *(const float4*)&biasP[(tj * 16 + wc * 8 + n * 4 + ((ln & 15) >> 2)) * 4];

    const int r_loc = wr * 16 + ((ln >> 4) << 2) + (ln & 3);
    const int u_loc0 = wc * 8 + ((ln & 15) >> 2);
    const int bg = ti * 64 + r_loc;
    unsigned int* myctr = &ctr[ti * 64];

    float c_reg[2] = {0.f, 0.f};

    // stage h chunk c_ into buffer buf_: 1 load/thread, dest wave-uniform
#define STAGE_H(buf_, c_) do { \
    const int r_ = wv * 8 + (ln >> 3); \
    const int so_ = ((ln & 7) << 4) ^ ((r_ & 7) << 4); \
    __builtin_amdgcn_global_load_lds( \
        (const __attribute__((address_space(1))) void*)(Ab + (size_t)r_ * 2048 + (c_) * 128 + so_), \
        (__attribute__((address_space(3))) void*)((char*)&lA[buf_][0] + wv * 1024), \
        16, 0, 0); \
} while (0)

    for (int t = 0; t < TT; ++t) {
        const unsigned short* hR = (t & 1) ? h1 : h0;
        unsigned short* hW = (t & 1) ? h0 : h1;

        // Xp -> registers (independent of h; issued before the poll)
        ushort4 xp4[2];
#pragma unroll
        for (int n = 0; n < 2; ++n)
            xp4[n] = *(const ushort4*)((const char*)Xp +
                        ((size_t)bg * TT + t) * 8192 + tj * 128 + (u_loc0 + n * 4) * 8);

        f32x4 acc[2] = {};

        if (t > 0) {
            // wait for all 64 same-ti producers of h(t-1)
            if (tid == 0) {
                const unsigned int want = 64u * (unsigned int)t;
                while (__hip_atomic_load(myctr, __ATOMIC_RELAXED, __HIP_MEMORY_SCOPE_AGENT) < want)
                    __builtin_amdgcn_s_sleep(2);
                (void)__hip_atomic_load(myctr, __ATOMIC_ACQUIRE, __HIP_MEMORY_SCOPE_AGENT);
            }
            __syncthreads();

            const char* Ab = (const char*)hR + (size_t)(ti * 64) * 2048;
            STAGE_H(0, 0);
            STAGE_H(1, 1);
#pragma unroll
            for (int c = 0; c < 16; ++c) {
                const int buf = c % 3;
                if (c < 15) { asm volatile("s_waitcnt vmcnt(1)" ::: "memory"); }
                else        { asm volatile("s_waitcnt vmcnt(0)" ::: "memory"); }
                __builtin_amdgcn_s_barrier();            // chunk c resident
                if (c < 14) STAGE_H((c + 2) % 3, c + 2); // overwrites c-1's buf (safe past barrier)

                bf16x8 af[2], bfr[2][2];
#pragma unroll
                for (int kk = 0; kk < 2; ++kk) {
                    {
                        const int row = wr * 16 + rlo;
                        const int off = (kk * 64 + khi * 16) ^ ((row & 7) << 4);
                        af[kk] = *(const bf16x8*)((const char*)&lA[buf][0] + row * 128 + off);
                    }
#pragma unroll
                    for (int n = 0; n < 2; ++n) {
                        const int row = wc * 32 + n * 16 + rlo;
                        const int off = (c * 128 + kk * 64 + khi * 16) ^ ((row & 7) << 4);
                        bfr[kk][n] = *(const bf16x8*)((const char*)lB + row * 2048 + off);
                    }
                }
                asm volatile("s_waitcnt lgkmcnt(0)" ::: "memory");
                __builtin_amdgcn_sched_barrier(0);
#pragma unroll
                for (int kk = 0; kk < 2; ++kk)
#pragma unroll
                    for (int n = 0; n < 2; ++n)
                        acc[n] = __builtin_amdgcn_mfma_f32_16x16x32_bf16(af[kk], bfr[kk][n], acc[n], 0, 0, 0);
            }
        }

        // ---- gate transpose (verified butterfly) + LSTM pointwise ----
#pragma unroll
        for (int n = 0; n < 2; ++n) {
            f32x4 v = acc[n], u, w;
#pragma unroll
            for (int k = 0; k < 4; ++k) {
                float s = __shfl_xor(v[k ^ 1], 1);
                u[k] = ((k & 1) == (ln & 1)) ? v[k] : s;
            }
#pragma unroll
            for (int k = 0; k < 4; ++k) {
                float s = __shfl_xor(u[k ^ 2], 2);
                w[k] = (((k >> 1) & 1) == ((ln >> 1) & 1)) ? u[k] : s;
            }
            const float gi = w[0] + bf2f(xp4[n].x) + bias4[n].x;
            const float gf = w[1] + bf2f(xp4[n].y) + bias4[n].y;
            const float gg = w[2] + bf2f(xp4[n].z) + bias4[n].z;
            const float go = w[3] + bf2f(xp4[n].w) + bias4[n].w;
            const float i_ = 1.f / (1.f + expf(-gi));
            const float f_ = 1.f / (1.f + expf(-gf));
            const float g_ = tanhf(gg);
            const float o_ = 1.f / (1.f + expf(-go));
            const float cc = f_ * c_reg[n] + i_ * g_;
            c_reg[n] = cc;
            const float h_ = o_ * tanhf(cc);
            const int ug = tj * 16 + u_loc0 + n * 4;
            __builtin_nontemporal_store(h_, &out1[(size_t)bg * (TT * HH) + (size_t)t * HH + ug]);
            hW[(size_t)bg * HH + ug] = f2bf(h_);
        }

        asm volatile("s_waitcnt vmcnt(0)" ::: "memory");
        __syncthreads();
        if (tid == 0)
            __hip_atomic_fetch_add(myctr, 1u, __ATOMIC_RELEASE, __HIP_MEMORY_SCOPE_AGENT);
    }
#undef STAGE_H
}

// ---------------------------------------------------------------------------
// Fallback per-step kernel (k_step3 from round 5, passing) — used only if
// cooperative launch is unavailable.
// ---------------------------------------------------------------------------
__global__ __launch_bounds__(512) void k_step3(
    const int t,
    const unsigned short* __restrict__ hbf,
    const unsigned short* __restrict__ WhhP,
    const unsigned short* __restrict__ Xp,
    const float* __restrict__ biasP,
    float* __restrict__ cbuf,
    unsigned short* __restrict__ hbf_out,
    float* __restrict__ out1)
{
    __shared__ unsigned short lA[3][64 * 128];
    __shared__ unsigned short lB[3][64 * 128];
    __shared__ unsigned short lXp[64 * 64];

    const int bid = blockIdx.x;
    const int ti = bid >> 6, tj = bid & 63;
    const int tid = threadIdx.x;
    const int wv = tid >> 6, ln = tid & 63;
    const int wr = wv >> 1, wc = wv & 1;
    const int rlo = ln & 15, khi = ln >> 4;

    {
        const size_t bg = (size_t)(ti * 64 + wv * 8 + (ln >> 3));
        __builtin_amdgcn_global_load_lds(
            (const __attribute__((address_space(1))) void*)((const char*)Xp + ((bg * TT + t) << 13) + tj * 128 + (ln & 7) * 16),
            (__attribute__((address_space(3))) void*)((char*)lXp + wv * 1024),
            16, 0, 0);
    }

    const char* Ab = (const char*)hbf + (size_t)(ti * 64) * 2048;
    const char* Bb = (const char*)WhhP + (size_t)(tj * 64) * 2048;

#define STAGE(buf_, c_) do { \
    _Pragma("unroll") \
    for (int q_ = 0; q_ < 2; ++q_) { \
        const int r_ = q_ * 32 + wv * 4 + (ln >> 4); \
        const int so_ = (((ln & 15) ^ (r_ & 7)) << 4); \
        __builtin_amdgcn_global_load_lds( \
            (const __attribute__((address_space(1))) void*)(Ab + (size_t)r_ * 2048 + (c_) * 256 + so_), \
            (__attribute__((address_space(3))) void*)((char*)&lA[buf_][0] + q_ * 8192 + wv * 1024), \
            16, 0, 0); \
        __builtin_amdgcn_global_load_lds( \
            (const __attribute__((address_space(1))) void*)(Bb + (size_t)r_ * 2048 + (c_) * 256 + so_), \
            (__attribute__((address_space(3))) void*)((char*)&lB[buf_][0] + q_ * 8192 + wv * 1024), \
            16, 0, 0); \
    } } while (0)

    STAGE(0, 0);
    STAGE(1, 1);
    STAGE(2, 2);

    float4 bias4[2];
#pragma unroll
    for (int n = 0; n < 2; ++n)
        bias4[n] = *(const float4*)&biasP[(tj * 16 + wc * 8 + n * 4 + ((ln & 15) >> 2)) * 4];

    f32x4 acc[2] = {};

#pragma unroll
    for (int c = 0; c < 8; ++c) {
        const int buf = c % 3;
        if (c < 6)       { asm volatile("s_waitcnt vmcnt(8)" ::: "memory"); }
        else if (c == 6) { asm volatile("s_waitcnt vmcnt(4)" ::: "memory"); }
        else             { asm volatile("s_waitcnt vmcnt(0)" ::: "memory"); }
        __builtin_amdgcn_s_barrier();

        bf16x8 af[4], bfr[4][2];
#pragma unroll
        for (int kk = 0; kk < 4; ++kk) {
            {
                const int row = wr * 16 + rlo;
                const int off = (kk * 64 + khi * 16) ^ ((row & 7) << 4);
                af[kk] = *(const bf16x8*)((const char*)&lA[buf][0] + row * 256 + off);
            }
#pragma unroll
            for (int n = 0; n < 2; ++n) {
                const int row = wc * 32 + n * 16 + rlo;
                const int off = (kk * 64 + khi * 16) ^ ((row & 7) << 4);
                bfr[kk][n] = *(const bf16x8*)((const char*)&lB[buf][0] + row * 256 + off);
            }
        }
        asm volatile("s_waitcnt lgkmcnt(0)" ::: "memory");
        __builtin_amdgcn_sched_barrier(0);
        __builtin_amdgcn_s_barrier();
        if (c < 5) STAGE((c + 3) % 3, c + 3);
#pragma unroll
        for (int kk = 0; kk < 4; ++kk)
#pragma unroll
            for (int n = 0; n < 2; ++n)
                acc[n] = __builtin_amdgcn_mfma_f32_16x16x32_bf16(af[kk], bfr[kk][n], acc[n], 0, 0, 0);
    }
#undef STAGE

#pragma unroll
    for (int n = 0; n < 2; ++n) {
        f32x4 v = acc[n], u, w;
#pragma unroll
        for (int k = 0; k < 4; ++k) {
            float s = __shfl_xor(v[k ^ 1], 1);
            u[k] = ((k & 1) == (ln & 1)) ? v[k] : s;
        }
#pragma unroll
        for (int k = 0; k < 4; ++k) {
            float s = __shfl_xor(u[k ^ 2], 2);
            w[k] = (((k >> 1) & 1) == ((ln >> 1) & 1)) ? u[k] : s;
        }
        const int r_loc = wr * 16 + ((ln >> 4) << 2) + (ln & 3);
        const int u_loc = wc * 8 + n * 4 + ((ln & 15) >> 2);
        const ushort4 xp4 = *(const ushort4*)((const char*)lXp + r_loc * 128 + u_loc * 8);
        const float gi = w[0] + bf2f(xp4.x) + bias4[n].x;
        const float gf = w[1] + bf2f(xp4.y) + bias4[n].y;
        const float gg = w[2] + bf2f(xp4.z) + bias4[n].z;
        const float go = w[3] + bf2f(xp4.w) + bias4[n].w;
        const float i_ = 1.f / (1.f + expf(-gi));
        const float f_ = 1.f / (1.f + expf(-gf));
        const float g_ = tanhf(gg);
        const float o_ = 1.f / (1.f + expf(-go));
        const int bg = ti * 64 + r_loc;
        const int ug = tj * 16 + u_loc;
        const float cprev = cbuf[(size_t)bg * HH + ug];
        const float cc = f_ * cprev + i_ * g_;
        cbuf[(size_t)bg * HH + ug] = cc;
        const float h_ = o_ * tanhf(cc);
        out1[(size_t)bg * (TT * HH) + (size_t)t * HH + ug] = h_;
        hbf_out[(size_t)bg * HH + ug] = f2bf(h_);
    }
}

// zero-init: clears hbf0|hbf1|cbuf/counters (2 MiB contiguous)
__global__ __launch_bounds__(256) void k_zero(float4* __restrict__ p)
{
    p[blockIdx.x * 256 + threadIdx.x] = make_float4(0.f, 0.f, 0.f, 0.f);
}

extern "C" void kernel_launch(void* const* d_in, const int* in_sizes, int n_in,
                              void* d_out, int out_size, void* d_ws, size_t ws_size,
                              hipStream_t stream)
{
    const float* x      = (const float*)d_in[0];
    const float* Wih    = (const float*)d_in[1];
    const float* Whh    = (const float*)d_in[2];
    const float* bih    = (const float*)d_in[3];
    const float* bhh    = (const float*)d_in[4];
    const float* attn_w = (const float*)d_in[5];
    const float* attn_b = (const float*)d_in[6];

    float* out0 = (float*)d_out;                               // (B,T,N)
    float* out1 = (float*)d_out + (size_t)BB * TT * NN;        // (B,T,H)

    char* w = (char*)d_ws;
    unsigned short* WihP  = (unsigned short*)(w);                       //  8 MiB
    unsigned short* WhhP  = (unsigned short*)(w + 8388608);             //  8 MiB
    float*          biasP = (float*)(w + 16777216);                     // 16 KiB
    unsigned short* winbf = (unsigned short*)(w + 16793600);            // 64 MiB
    unsigned short* Xp    = (unsigned short*)(w + 83902464);            // 256 MiB
    unsigned short* hbf0  = (unsigned short*)(w + 352337920);           // 512 KiB
    unsigned short* hbf1  = (unsigned short*)(w + 352862208);           // 512 KiB
    float*          cbuf  = (float*)(w + 353386496);                    //   1 MiB (cbuf / counters)

    k_attn<<<BB, 512, 0, stream>>>(x, attn_w, attn_b, out0, winbf);
    k_prep_w<<<G4, 256, 0, stream>>>(Wih, Whh, bih, bhh, WihP, WhhP, biasP);
    k_gemm_xp<<<(BB * TT / 128) * (G4 / 128), 256, 0, stream>>>(winbf, WihP, Xp);
    k_zero<<<512, 256, 0, stream>>>((float4*)hbf0);   // h0/h1/counters = 0

    // persistent recurrence (cooperative launch for residency; NO grid.sync)
    {
        const unsigned short* WhhP_c = WhhP;
        const unsigned short* Xp_c = Xp;
        const float* biasP_c = biasP;
        unsigned short* h0_c = hbf0;
        unsigned short* h1_c = hbf1;
        unsigned int* ctr_c = (unsigned int*)cbuf;
        float* out1_c = out1;
        void* args[] = { (void*)&WhhP_c, (void*)&Xp_c, (void*)&biasP_c,
                         (void*)&h0_c, (void*)&h1_c, (void*)&ctr_c, (void*)&out1_c };
        hipError_t err = hipLaunchCooperativeKernel((void*)k_recur2, dim3(256), dim3(512),
                                                    args, 0, stream);
        if (err != hipSuccess) {
            // fallback: per-step launches (round-5 passing path)
            for (int t = 0; t < TT; ++t) {
                const unsigned short* hin = (t & 1) ? hbf1 : hbf0;
                unsigned short* hout      = (t & 1) ? hbf0 : hbf1;
                k_step3<<<256, 512, 0, stream>>>(t, hin, WhhP, Xp, biasP, cbuf, hout, out1);
            }
        }
    }
}

// Round 7
// 2232.330 us; speedup vs baseline: 1.2234x; 1.2234x over previous
//
#include <hip/hip_runtime.h>
#include <hip/hip_bf16.h>

#define BB 256
#define TT 128
#define NN 1024
#define HH 1024
#define G4 4096

typedef __attribute__((ext_vector_type(4))) float f32x4;
typedef __attribute__((ext_vector_type(8))) short bf16x8;

__device__ __forceinline__ unsigned short f2bf(float f) {
    unsigned int u = __builtin_bit_cast(unsigned int, f);
    u += 0x7FFFu + ((u >> 16) & 1u);
    return (unsigned short)(u >> 16);
}
__device__ __forceinline__ float bf2f(unsigned short s) {
    unsigned int u = ((unsigned int)s) << 16;
    return __builtin_bit_cast(float, u);
}

// ---------------------------------------------------------------------------
// K1: attention weights (time-invariant) + input_weighted (f32) + w_in bf16
// ---------------------------------------------------------------------------
__global__ __launch_bounds__(512) void k_attn(
    const float* __restrict__ x, const float* __restrict__ attn_w,
    const float* __restrict__ attn_b, float* __restrict__ out0,
    unsigned short* __restrict__ win_bf)
{
    const int b = blockIdx.x;
    const int tid = threadIdx.x;
    const float* xb = x + (size_t)b * (TT * NN);
    const float* wx = attn_w + 2 * HH;

    float s0 = 0.f, s1 = 0.f;
    for (int t = 0; t < TT; ++t) {
        float2 v = *(const float2*)(xb + (size_t)t * NN + tid * 2);
        float w = wx[t];
        s0 += v.x * w; s1 += v.y * w;
    }
    float ab = attn_b[0];
    s0 += ab; s1 += ab;

    __shared__ float red[8];
    const int wv = tid >> 6, ln = tid & 63;
    float m = fmaxf(s0, s1);
#pragma unroll
    for (int off = 32; off > 0; off >>= 1) m = fmaxf(m, __shfl_xor(m, off));
    if (ln == 0) red[wv] = m;
    __syncthreads();
    m = red[0];
#pragma unroll
    for (int i = 1; i < 8; ++i) m = fmaxf(m, red[i]);

    float e0 = expf(s0 - m), e1 = expf(s1 - m);
    float sum = e0 + e1;
#pragma unroll
    for (int off = 32; off > 0; off >>= 1) sum += __shfl_xor(sum, off);
    __syncthreads();
    if (ln == 0) red[wv] = sum;
    __syncthreads();
    sum = 0.f;
#pragma unroll
    for (int i = 0; i < 8; ++i) sum += red[i];
    const float inv = 1.0f / sum;
    const float a0 = e0 * inv, a1 = e1 * inv;

    float* o = out0 + (size_t)b * (TT * NN);
    unsigned short* wb = win_bf + (size_t)b * (TT * NN);
    for (int t = 0; t < TT; ++t) {
        float2 v = *(const float2*)(xb + (size_t)t * NN + tid * 2);
        float2 w; w.x = a0 * v.x; w.y = a1 * v.y;
        *(float2*)(o + (size_t)t * NN + tid * 2) = w;
        unsigned int pk = (unsigned int)f2bf(w.x) | ((unsigned int)f2bf(w.y) << 16);
        *(unsigned int*)(wb + (size_t)t * NN + tid * 2) = pk;
    }
}

// ---------------------------------------------------------------------------
// K2: convert W_ih / W_hh to bf16 with gate-interleaved row perm p=j*4+g
// ---------------------------------------------------------------------------
__global__ __launch_bounds__(256) void k_prep_w(
    const float* __restrict__ Wih, const float* __restrict__ Whh,
    const float* __restrict__ bih, const float* __restrict__ bhh,
    unsigned short* __restrict__ WihP, unsigned short* __restrict__ WhhP,
    float* __restrict__ biasP)
{
    const int p = blockIdx.x;
    const int j = p >> 2, g = p & 3;
    const int r = g * HH + j;
    const int tid = threadIdx.x;
    {
        float4 v = *(const float4*)(Wih + (size_t)r * NN + tid * 4);
        ushort4 o;
        o.x = f2bf(v.x); o.y = f2bf(v.y); o.z = f2bf(v.z); o.w = f2bf(v.w);
        *(ushort4*)(WihP + (size_t)p * NN + tid * 4) = o;
    }
    {
        float4 v = *(const float4*)(Whh + (size_t)r * HH + tid * 4);
        ushort4 o;
        o.x = f2bf(v.x); o.y = f2bf(v.y); o.z = f2bf(v.z); o.w = f2bf(v.w);
        *(ushort4*)(WhhP + (size_t)p * HH + tid * 4) = o;
    }
    if (tid == 0) biasP[p] = bih[r] + bhh[r];
}

// ---------------------------------------------------------------------------
// K3: Xp = w_in_bf16 (32768,1024) @ WihP^T (4096,1024) -> bf16 (32768,4096)
// ---------------------------------------------------------------------------
__global__ __launch_bounds__(256) void k_gemm_xp(
    const unsigned short* __restrict__ A,
    const unsigned short* __restrict__ Bm,
    unsigned short* __restrict__ C)
{
    __shared__ unsigned short lA[128 * 32];
    __shared__ unsigned short lB[128 * 32];

    const int bid = blockIdx.x;
    const int cpx = gridDim.x >> 3;
    const int swz = (bid & 7) * cpx + (bid >> 3);
    const int NTN = G4 / 128;
    const int tm = swz / NTN, tn = swz % NTN;

    const int tid = threadIdx.x;
    const int wv = tid >> 6, ln = tid & 63;
    const int wr = wv >> 1, wc = wv & 1;

    f32x4 acc[4][4] = {};

    const unsigned short* Ag = A + (size_t)tm * 128 * NN;
    const unsigned short* Bg = Bm + (size_t)tn * 128 * NN;
    const int srow = ln >> 2;
    const int sseg = ln & 3;

    for (int k0 = 0; k0 < NN; k0 += 32) {
        __syncthreads();
#pragma unroll
        for (int q = 0; q < 2; ++q) {
            const int row = wv * 32 + q * 16 + srow;
            __builtin_amdgcn_global_load_lds(
                (const __attribute__((address_space(1))) void*)(Ag + (size_t)row * NN + k0 + sseg * 8),
                (__attribute__((address_space(3))) void*)(&lA[(wv * 32 + q * 16) * 32]),
                16, 0, 0);
            __builtin_amdgcn_global_load_lds(
                (const __attribute__((address_space(1))) void*)(Bg + (size_t)row * NN + k0 + sseg * 8),
                (__attribute__((address_space(3))) void*)(&lB[(wv * 32 + q * 16) * 32]),
                16, 0, 0);
        }
        __syncthreads();

        const int rlo = ln & 15, khi = ln >> 4;
        bf16x8 af[4], bfr[4];
#pragma unroll
        for (int m = 0; m < 4; ++m)
            af[m] = *(const bf16x8*)&lA[(wr * 64 + m * 16 + rlo) * 32 + khi * 8];
#pragma unroll
        for (int n = 0; n < 4; ++n)
            bfr[n] = *(const bf16x8*)&lB[(wc * 64 + n * 16 + rlo) * 32 + khi * 8];
#pragma unroll
        for (int m = 0; m < 4; ++m)
#pragma unroll
            for (int n = 0; n < 4; ++n)
                acc[m][n] = __builtin_amdgcn_mfma_f32_16x16x32_bf16(af[m], bfr[n], acc[m][n], 0, 0, 0);
    }

    const int rlo = ln & 15, rhi = ln >> 4;
#pragma unroll
    for (int m = 0; m < 4; ++m)
#pragma unroll
        for (int n = 0; n < 4; ++n)
#pragma unroll
            for (int j = 0; j < 4; ++j) {
                const int row = tm * 128 + wr * 64 + m * 16 + rhi * 4 + j;
                const int col = tn * 128 + wc * 64 + n * 16 + rlo;
                C[(size_t)row * G4 + col] = f2bf(acc[m][n][j]);
            }
}

// ---------------------------------------------------------------------------
// K4 v4 (per step): barrier-light. 256 blocks x 512 threads (8 waves).
//   Block (ti,tj): 64 batches x 64 perm-cols. Wave (wr=wv>>1 0..3, wc=wv&1):
//   16 rows x 32 cols. A (h) global->registers, compiler-pipelined, full
//   16-chunk unroll. B (W_hh slice) reg-staged to LDS in two 64KiB halves
//   (XOR-swizzled ds_write); ONLY 2 raw s_barriers per step, each gated by
//   lgkmcnt(0) only (no vmcnt drain). Epilogue = verified butterfly.
// ---------------------------------------------------------------------------
__global__ __launch_bounds__(512, 2) void k_step4(
    const int t,
    const unsigned short* __restrict__ hbf,
    const unsigned short* __restrict__ WhhP,
    const unsigned short* __restrict__ Xp,
    const float* __restrict__ biasP,
    float* __restrict__ cbuf,
    unsigned short* __restrict__ hbf_out,
    float* __restrict__ out1)
{
    __shared__ unsigned short lB[64 * 1024];   // 128 KiB, [Wcol 64][k 1024] swizzled

    const int bid = blockIdx.x;
    const int ti = bid >> 6, tj = bid & 63;
    const int tid = threadIdx.x;
    const int wv = tid >> 6, ln = tid & 63;
    const int wr = wv >> 1, wc = wv & 1;
    const int rlo = ln & 15, khi = ln >> 4;
    const int khi16 = khi * 16;

    const char* Ab = (const char*)hbf + (size_t)(ti * 64) * 2048;
    const char* Bb = (const char*)WhhP + (size_t)(tj * 64) * 2048;

    // ---- epilogue coords (verified in k_recur2) ----
    const int r_loc = wr * 16 + ((ln >> 4) << 2) + (ln & 3);
    const int u_loc0 = wc * 8 + ((ln & 15) >> 2);
    const int bg = ti * 64 + r_loc;

    // ---- Xp + cprev + bias to regs (issued earliest) ----
    ushort4 xp4[2];
    float cp[2];
    float4 bias4[2];
#pragma unroll
    for (int n = 0; n < 2; ++n) {
        xp4[n] = *(const ushort4*)((const char*)Xp +
                    ((size_t)bg * TT + t) * 8192 + tj * 128 + (u_loc0 + n * 4) * 8);
        cp[n] = cbuf[(size_t)bg * HH + tj * 16 + u_loc0 + n * 4];
        bias4[n] = *(const float4*)&biasP[(tj * 16 + u_loc0 + n * 4) * 4];
    }

    // ---- B stage coords: thread -> (srow = tid>>3, sseg = tid&7) ----
    const int srow = tid >> 3;
    const int sseg = tid & 7;
    const int sswz = (srow & 7) << 4;

    // ---- Bh1 global loads (k bytes 0..1023) ----
    bf16x8 bh1[8];
#pragma unroll
    for (int j = 0; j < 8; ++j)
        bh1[j] = *(const bf16x8*)(Bb + (size_t)srow * 2048 + (sseg + j * 8) * 16);

    // ---- A chunk loads 0..7 ----
    const char* abase = Ab + (size_t)(wr * 16 + rlo) * 2048 + khi16;
#define LOADA(c) \
    const bf16x8 a0_##c = *(const bf16x8*)(abase + (c) * 128); \
    const bf16x8 a1_##c = *(const bf16x8*)(abase + (c) * 128 + 64);
    LOADA(0) LOADA(1) LOADA(2) LOADA(3) LOADA(4) LOADA(5) LOADA(6) LOADA(7)

    // ---- Bh2 global loads (k bytes 1024..2047) ----
    bf16x8 bh2[8];
#pragma unroll
    for (int j = 0; j < 8; ++j)
        bh2[j] = *(const bf16x8*)(Bb + (size_t)srow * 2048 + 1024 + (sseg + j * 8) * 16);

    // ---- write Bh1 to LDS (swizzled) ----
    char* lw = (char*)lB + (size_t)srow * 2048;
#pragma unroll
    for (int j = 0; j < 8; ++j)
        *(bf16x8*)(lw + (((sseg + j * 8) * 16) ^ sswz)) = bh1[j];

    asm volatile("s_waitcnt lgkmcnt(0)" ::: "memory");
    __builtin_amdgcn_sched_barrier(0);
    __builtin_amdgcn_s_barrier();              // Bh1 visible; Bh2/A still in flight

    // ---- B read bases ----
    const int brow0 = wc * 32 + rlo;           // n=0 rows; n=1 rows = +16 (same swz)
    const int bswz = (brow0 & 7) << 4;
    const char* lb0 = (const char*)lB + (size_t)brow0 * 2048;
    const char* lb1 = lb0 + 16 * 2048;
    const int okk0 = khi16 ^ bswz;
    const int okk1 = (64 + khi16) ^ bswz;

    f32x4 acc[2] = {};

#define CHUNK(c) do { \
    const bf16x8 b00 = *(const bf16x8*)(lb0 + (c) * 128 + okk0); \
    const bf16x8 b01 = *(const bf16x8*)(lb0 + (c) * 128 + okk1); \
    const bf16x8 b10 = *(const bf16x8*)(lb1 + (c) * 128 + okk0); \
    const bf16x8 b11 = *(const bf16x8*)(lb1 + (c) * 128 + okk1); \
    acc[0] = __builtin_amdgcn_mfma_f32_16x16x32_bf16(a0_##c, b00, acc[0], 0, 0, 0); \
    acc[1] = __builtin_amdgcn_mfma_f32_16x16x32_bf16(a0_##c, b10, acc[1], 0, 0, 0); \
    acc[0] = __builtin_amdgcn_mfma_f32_16x16x32_bf16(a1_##c, b01, acc[0], 0, 0, 0); \
    acc[1] = __builtin_amdgcn_mfma_f32_16x16x32_bf16(a1_##c, b11, acc[1], 0, 0, 0); \
} while (0)

    CHUNK(0); CHUNK(1); CHUNK(2);

    // write Bh2 to LDS (h2 region untouched by chunk 0-7 reads)
#pragma unroll
    for (int j = 0; j < 8; ++j)
        *(bf16x8*)(lw + 1024 + (((sseg + j * 8) * 16) ^ sswz)) = bh2[j];

    CHUNK(3); CHUNK(4);
    LOADA(8) LOADA(9) LOADA(10) LOADA(11)
    CHUNK(5); CHUNK(6);
    LOADA(12) LOADA(13) LOADA(14) LOADA(15)
    CHUNK(7);

    asm volatile("s_waitcnt lgkmcnt(0)" ::: "memory");
    __builtin_amdgcn_sched_barrier(0);
    __builtin_amdgcn_s_barrier();              // Bh2 visible

    CHUNK(8); CHUNK(9); CHUNK(10); CHUNK(11);
    CHUNK(12); CHUNK(13); CHUNK(14); CHUNK(15);
#undef CHUNK
#undef LOADA

    // ---- gate transpose (verified butterfly) + LSTM pointwise ----
#pragma unroll
    for (int n = 0; n < 2; ++n) {
        f32x4 v = acc[n], u, w;
#pragma unroll
        for (int k = 0; k < 4; ++k) {
            float s = __shfl_xor(v[k ^ 1], 1);
            u[k] = ((k & 1) == (ln & 1)) ? v[k] : s;
        }
#pragma unroll
        for (int k = 0; k < 4; ++k) {
            float s = __shfl_xor(u[k ^ 2], 2);
            w[k] = (((k >> 1) & 1) == ((ln >> 1) & 1)) ? u[k] : s;
        }
        const float gi = w[0] + bf2f(xp4[n].x) + bias4[n].x;
        const float gf = w[1] + bf2f(xp4[n].y) + bias4[n].y;
        const float gg = w[2] + bf2f(xp4[n].z) + bias4[n].z;
        const float go = w[3] + bf2f(xp4[n].w) + bias4[n].w;
        const float i_ = 1.f / (1.f + expf(-gi));
        const float f_ = 1.f / (1.f + expf(-gf));
        const float g_ = tanhf(gg);
        const float o_ = 1.f / (1.f + expf(-go));
        const float cc = f_ * cp[n] + i_ * g_;
        const float h_ = o_ * tanhf(cc);
        const int ug = tj * 16 + u_loc0 + n * 4;
        cbuf[(size_t)bg * HH + ug] = cc;
        out1[(size_t)bg * (TT * HH) + (size_t)t * HH + ug] = h_;
        hbf_out[(size_t)bg * HH + ug] = f2bf(h_);
    }
}

// zero-init: clears hbf0|hbf1|cbuf (2 MiB contiguous)
__global__ __launch_bounds__(256) void k_zero(float4* __restrict__ p)
{
    p[blockIdx.x * 256 + threadIdx.x] = make_float4(0.f, 0.f, 0.f, 0.f);
}

extern "C" void kernel_launch(void* const* d_in, const int* in_sizes, int n_in,
                              void* d_out, int out_size, void* d_ws, size_t ws_size,
                              hipStream_t stream)
{
    const float* x      = (const float*)d_in[0];
    const float* Wih    = (const float*)d_in[1];
    const float* Whh    = (const float*)d_in[2];
    const float* bih    = (const float*)d_in[3];
    const float* bhh    = (const float*)d_in[4];
    const float* attn_w = (const float*)d_in[5];
    const float* attn_b = (const float*)d_in[6];

    float* out0 = (float*)d_out;                               // (B,T,N)
    float* out1 = (float*)d_out + (size_t)BB * TT * NN;        // (B,T,H)

    char* w = (char*)d_ws;
    unsigned short* WihP  = (unsigned short*)(w);                       //  8 MiB
    unsigned short* WhhP  = (unsigned short*)(w + 8388608);             //  8 MiB
    float*          biasP = (float*)(w + 16777216);                     // 16 KiB
    unsigned short* winbf = (unsigned short*)(w + 16793600);            // 64 MiB
    unsigned short* Xp    = (unsigned short*)(w + 83902464);            // 256 MiB
    unsigned short* hbf0  = (unsigned short*)(w + 352337920);           // 512 KiB
    unsigned short* hbf1  = (unsigned short*)(w + 352862208);           // 512 KiB
    float*          cbuf  = (float*)(w + 353386496);                    //   1 MiB

    k_attn<<<BB, 512, 0, stream>>>(x, attn_w, attn_b, out0, winbf);
    k_prep_w<<<G4, 256, 0, stream>>>(Wih, Whh, bih, bhh, WihP, WhhP, biasP);
    k_gemm_xp<<<(BB * TT / 128) * (G4 / 128), 256, 0, stream>>>(winbf, WihP, Xp);
    k_zero<<<512, 256, 0, stream>>>((float4*)hbf0);   // h(t=0)=0, c=0

    for (int t = 0; t < TT; ++t) {
        const unsigned short* hin = (t & 1) ? hbf1 : hbf0;
        unsigned short* hout      = (t & 1) ? hbf0 : hbf1;
        k_step4<<<256, 512, 0, stream>>>(t, hin, WhhP, Xp, biasP, cbuf, hout, out1);
    }
}